// Round 1
// baseline (666.286 us; speedup 1.0000x reference)
//
#include <hip/hip_runtime.h>
#include <hip/hip_bf16.h>

#define VOCAB 1000000
#define EMB 128
#define NEG 512
#define BATCH 16384

#define BM 64
#define BN 64
#define KE 160          // 128 real K + 32 ext slots (const folded into GEMM)
#define LDSTR 168       // LDS row stride in bf16 elems: 336B, 16B-aligned, 2-way-bank-free

#define NMAIN ((BATCH / BM) * (NEG / BN))   // 2048
#define NTRUE_BLK (BATCH / 4)               // 4096 (4 rows per block, wave-per-row)
#define NBLK (NMAIN + NTRUE_BLK)            // 6144

typedef __attribute__((ext_vector_type(8))) short bf16x8;
typedef __attribute__((ext_vector_type(4))) float f32x4;

static __device__ __forceinline__ unsigned short f2bf(float f) {
    union { __hip_bfloat16 b; unsigned short u; } cv;
    cv.b = __float2bfloat16(f);
    return cv.u;
}
static __device__ __forceinline__ float bf2f(unsigned short u) {
    union { unsigned short u; __hip_bfloat16 b; } cv;
    cv.u = u;
    return __bfloat162float(cv.b);
}

// -log(expected_count(c)) per TF LogUniformCandidateSampler.
// CRITICAL: p via log1p(1/(c+1)), NOT log(c+2)-log(c+1) — the latter
// cancels to 0 in fp32 for c ~ 1e6, giving E=0 -> -log(0)=inf -> NaN.
static __device__ __forceinline__ float neg_log_expected(int c) {
    float cf = (float)c;
    float p = log1pf(1.0f / (cf + 1.0f)) / logf((float)VOCAB + 1.0f);
    float E = -expm1f((float)NEG * log1pf(-p));
    return -logf(E);
}

// d_out accumulator must start at 0 each iteration (atomicAdd accumulation).
__global__ __launch_bounds__(64) void zero_k(float* __restrict__ out) {
    if (threadIdx.x == 0) out[0] = 0.0f;
}

// Single fused kernel: NO workspace usage at all.
//  - blocks [0, NMAIN): 64x64 sampled-logit GEMM tiles; B-tile gathered from
//    weights[sampled[...]] with in-flight fp32->bf16 conversion and the
//    (bias - log E) constant folded into K-ext slots 128/129 as a 2-way bf16 split.
//  - blocks [NMAIN, NBLK): true-label path, wave-per-row, fp32 exact.
// Each block atomicAdds its (already 1/BATCH-scaled) loss into out[0].
__global__ __launch_bounds__(256) void main_k(const float* __restrict__ pred,
                                              const float* __restrict__ weights,
                                              const float* __restrict__ biases,
                                              const int* __restrict__ labels,
                                              const int* __restrict__ sampled,
                                              float* __restrict__ out) {
    __shared__ unsigned short As[BM * LDSTR];
    __shared__ unsigned short Bs[BN * LDSTR];
    __shared__ float red[4];
    int bid = blockIdx.x;
    int tid = threadIdx.x;
    int lane = tid & 63;
    int wv = tid >> 6;

    const float inv_batch = 1.0f / (float)BATCH;

    if (bid < NMAIN) {
        // ---- sampled-logits GEMM tile: 64 rows x 64 samples ----
        int m0 = (bid >> 3) * BM;
        int s0 = (bid & 7) * BN;

        // stage A (pred rows, fp32 -> bf16), k-contiguous
        const float4* pred4 = (const float4*)pred;
#pragma unroll
        for (int i = 0; i < 8; ++i) {
            int l = tid + i * 256;
            int row = l >> 5, k4 = l & 31;
            float4 v = pred4[(size_t)(m0 + row) * 32 + k4];
            uint2 p;
            p.x = (unsigned)f2bf(v.x) | ((unsigned)f2bf(v.y) << 16);
            p.y = (unsigned)f2bf(v.z) | ((unsigned)f2bf(v.w) << 16);
            *(uint2*)&As[row * LDSTR + k4 * 4] = p;
        }
        // stage A ext slots: [128]=[129]=1.0 (bf16 0x3F80), rest 0
#pragma unroll
        for (int i = 0; i < 8; ++i) {
            int l = tid + i * 256;
            int row = l >> 5, sl = l & 31;
            As[row * LDSTR + 128 + sl] = (sl < 2) ? (unsigned short)0x3F80 : (unsigned short)0;
        }
        // stage B: gather sampled weight rows directly from fp32 weights,
        // convert to bf16 in-flight (replaces the old prep_k + swe workspace)
        const float4* w4 = (const float4*)weights;
#pragma unroll
        for (int i = 0; i < 8; ++i) {
            int l = tid + i * 256;
            int row = l >> 5, k4 = l & 31;
            int sid = sampled[s0 + row];
            float4 v = w4[(size_t)sid * 32 + k4];
            uint2 p;
            p.x = (unsigned)f2bf(v.x) | ((unsigned)f2bf(v.y) << 16);
            p.y = (unsigned)f2bf(v.z) | ((unsigned)f2bf(v.w) << 16);
            *(uint2*)&Bs[row * LDSTR + k4 * 4] = p;
        }
        // stage B ext slots: [128]=c_hi, [129]=c_lo (2-way bf16 split of
        // bias - log(E)), [130..159]=0
#pragma unroll
        for (int i = 0; i < 8; ++i) {
            int l = tid + i * 256;
            int row = l >> 5, sl = l & 31;
            unsigned short v = 0;
            if (sl < 2) {
                int sid = sampled[s0 + row];
                float c = biases[sid] + neg_log_expected(sid);
                unsigned short hi = f2bf(c);
                v = (sl == 0) ? hi : f2bf(c - bf2f(hi));
            }
            Bs[row * LDSTR + 128 + sl] = v;
        }
        __syncthreads();

        int wm = (wv & 1) * 32;
        int wn = (wv >> 1) * 32;
        int fr = lane & 15;
        int kq = (lane >> 4) * 8;

        f32x4 zero = {0.0f, 0.0f, 0.0f, 0.0f};
        f32x4 acc00 = zero, acc01 = zero, acc10 = zero, acc11 = zero;
#pragma unroll
        for (int kc = 0; kc < KE; kc += 32) {
            int kk = kc + kq;
            bf16x8 a0 = *(const bf16x8*)&As[(wm + fr) * LDSTR + kk];
            bf16x8 a1 = *(const bf16x8*)&As[(wm + 16 + fr) * LDSTR + kk];
            bf16x8 b0 = *(const bf16x8*)&Bs[(wn + fr) * LDSTR + kk];
            bf16x8 b1 = *(const bf16x8*)&Bs[(wn + 16 + fr) * LDSTR + kk];
            acc00 = __builtin_amdgcn_mfma_f32_16x16x32_bf16(a0, b0, acc00, 0, 0, 0);
            acc01 = __builtin_amdgcn_mfma_f32_16x16x32_bf16(a0, b1, acc01, 0, 0, 0);
            acc10 = __builtin_amdgcn_mfma_f32_16x16x32_bf16(a1, b0, acc10, 0, 0, 0);
            acc11 = __builtin_amdgcn_mfma_f32_16x16x32_bf16(a1, b1, acc11, 0, 0, 0);
        }
        // every acc element is a finished sampled logit (const baked in via K-ext)
        float loss = 0.0f;
#pragma unroll
        for (int r = 0; r < 4; ++r) {
            float x;
            x = acc00[r]; loss += fmaxf(x, 0.0f) + log1pf(expf(-fabsf(x)));
            x = acc01[r]; loss += fmaxf(x, 0.0f) + log1pf(expf(-fabsf(x)));
            x = acc10[r]; loss += fmaxf(x, 0.0f) + log1pf(expf(-fabsf(x)));
            x = acc11[r]; loss += fmaxf(x, 0.0f) + log1pf(expf(-fabsf(x)));
        }
#pragma unroll
        for (int off = 32; off > 0; off >>= 1) loss += __shfl_xor(loss, off);
        if (lane == 0) red[wv] = loss;
        __syncthreads();
        if (tid == 0)
            atomicAdd(out, (red[0] + red[1] + red[2] + red[3]) * inv_batch);
    } else {
        // ---- true-label path: wave-per-row, fp32 exact ----
        int b = (bid - NMAIN) * 4 + wv;
        int lbl = labels[b];
        float2 a = ((const float2*)pred)[(size_t)b * 64 + lane];
        float2 w = ((const float2*)weights)[(size_t)lbl * 64 + lane];
        float dot = a.x * w.x + a.y * w.y;
#pragma unroll
        for (int off = 32; off > 0; off >>= 1) dot += __shfl_xor(dot, off);
        if (lane == 0) {
            float x = dot + biases[lbl] + neg_log_expected(lbl);
            // sigmoid CE with z = 1/NTRUE = 1
            red[wv] = fmaxf(x, 0.0f) - x + log1pf(expf(-fabsf(x)));
        }
        __syncthreads();
        if (tid == 0)
            atomicAdd(out, (red[0] + red[1] + red[2] + red[3]) * inv_batch);
    }
}

extern "C" void kernel_launch(void* const* d_in, const int* in_sizes, int n_in,
                              void* d_out, int out_size, void* d_ws, size_t ws_size,
                              hipStream_t stream) {
    const float* pred    = (const float*)d_in[0];
    const float* weights = (const float*)d_in[1];
    const float* biases  = (const float*)d_in[2];
    const int*   labels  = (const int*)d_in[3];
    const int*   sampled = (const int*)d_in[4];
    float* out = (float*)d_out;

    // NOTE: d_ws deliberately untouched — testing whether the per-iteration
    // 2 GB workspace re-poison fill (the ~320 µs dispatches dominating the
    // profile) is usage-conditional.
    (void)d_ws; (void)ws_size;

    zero_k<<<dim3(1), dim3(64), 0, stream>>>(out);
    main_k<<<dim3(NBLK), dim3(256), 0, stream>>>(pred, weights, biases, labels, sampled, out);
}

// Round 2
// 636.924 us; speedup vs baseline: 1.0461x; 1.0461x over previous
//
#include <hip/hip_runtime.h>
#include <hip/hip_bf16.h>

#define VOCAB 1000000
#define EMB 128
#define NEG 512
#define BATCH 16384

#define BM 64
#define BN 64
#define KE 160          // 128 real K + 32 ext slots (const folded into GEMM)
#define LDSTR 168       // LDS row stride in bf16 elems: 336B, 16B-aligned, 2-way-bank-free

#define NMAIN ((BATCH / BM) * (NEG / BN))   // 2048
#define NTRUE_BLK (BATCH / 4)               // 4096 (4 rows per block, wave-per-row)
#define NBLK (NMAIN + NTRUE_BLK)            // 6144

typedef __attribute__((ext_vector_type(8))) short bf16x8;
typedef __attribute__((ext_vector_type(4))) float f32x4;

static __device__ __forceinline__ unsigned short f2bf(float f) {
    union { __hip_bfloat16 b; unsigned short u; } cv;
    cv.b = __float2bfloat16(f);
    return cv.u;
}
static __device__ __forceinline__ float bf2f(unsigned short u) {
    union { unsigned short u; __hip_bfloat16 b; } cv;
    cv.u = u;
    return __bfloat162float(cv.b);
}

// -log(expected_count(c)) per TF LogUniformCandidateSampler.
// CRITICAL: p via log1p(1/(c+1)), NOT log(c+2)-log(c+1) — the latter
// cancels to 0 in fp32 for c ~ 1e6, giving E=0 -> -log(0)=inf -> NaN.
static __device__ __forceinline__ float neg_log_expected(int c) {
    float cf = (float)c;
    float p = log1pf(1.0f / (cf + 1.0f)) / logf((float)VOCAB + 1.0f);
    float E = -expm1f((float)NEG * log1pf(-p));
    return -logf(E);
}

// Fused kernel (prep folded in; NO cross-block atomics — R1 showed 6144
// same-address device atomics cost ~+60us from end-of-kernel pile-up):
//  - blocks [0, NMAIN): 64x64 sampled-logit GEMM tiles; B-tile gathered from
//    weights[sampled[...]] with in-flight fp32->bf16 conversion and the
//    (bias - log E) constant folded into K-ext slots 128/129 as a 2-way bf16 split.
//  - blocks [NMAIN, NBLK): true-label path, wave-per-row, fp32 exact.
// Each block writes its unscaled loss to partials[bid] (workspace — the 2 GB
// re-poison fill is unconditional per R1, so ws use is free).
__global__ __launch_bounds__(256) void main_k(const float* __restrict__ pred,
                                              const float* __restrict__ weights,
                                              const float* __restrict__ biases,
                                              const int* __restrict__ labels,
                                              const int* __restrict__ sampled,
                                              float* __restrict__ partials) {
    __shared__ unsigned short As[BM * LDSTR];
    __shared__ unsigned short Bs[BN * LDSTR];
    __shared__ float red[4];
    int bid = blockIdx.x;
    int tid = threadIdx.x;
    int lane = tid & 63;
    int wv = tid >> 6;

    if (bid < NMAIN) {
        // ---- sampled-logits GEMM tile: 64 rows x 64 samples ----
        int m0 = (bid >> 3) * BM;
        int s0 = (bid & 7) * BN;

        // stage A (pred rows, fp32 -> bf16), k-contiguous
        const float4* pred4 = (const float4*)pred;
#pragma unroll
        for (int i = 0; i < 8; ++i) {
            int l = tid + i * 256;
            int row = l >> 5, k4 = l & 31;
            float4 v = pred4[(size_t)(m0 + row) * 32 + k4];
            uint2 p;
            p.x = (unsigned)f2bf(v.x) | ((unsigned)f2bf(v.y) << 16);
            p.y = (unsigned)f2bf(v.z) | ((unsigned)f2bf(v.w) << 16);
            *(uint2*)&As[row * LDSTR + k4 * 4] = p;
        }
        // stage A ext slots: [128]=[129]=1.0 (bf16 0x3F80), rest 0
#pragma unroll
        for (int i = 0; i < 8; ++i) {
            int l = tid + i * 256;
            int row = l >> 5, sl = l & 31;
            As[row * LDSTR + 128 + sl] = (sl < 2) ? (unsigned short)0x3F80 : (unsigned short)0;
        }
        // stage B: gather sampled weight rows directly from fp32 weights,
        // convert to bf16 in-flight (prep_k fused; rows are L2-hot: 512
        // unique rows = 256 KB)
        const float4* w4 = (const float4*)weights;
#pragma unroll
        for (int i = 0; i < 8; ++i) {
            int l = tid + i * 256;
            int row = l >> 5, k4 = l & 31;
            int sid = sampled[s0 + row];
            float4 v = w4[(size_t)sid * 32 + k4];
            uint2 p;
            p.x = (unsigned)f2bf(v.x) | ((unsigned)f2bf(v.y) << 16);
            p.y = (unsigned)f2bf(v.z) | ((unsigned)f2bf(v.w) << 16);
            *(uint2*)&Bs[row * LDSTR + k4 * 4] = p;
        }
        // stage B ext slots: [128]=c_hi, [129]=c_lo (2-way bf16 split of
        // bias - log(E)), [130..159]=0
#pragma unroll
        for (int i = 0; i < 8; ++i) {
            int l = tid + i * 256;
            int row = l >> 5, sl = l & 31;
            unsigned short v = 0;
            if (sl < 2) {
                int sid = sampled[s0 + row];
                float c = biases[sid] + neg_log_expected(sid);
                unsigned short hi = f2bf(c);
                v = (sl == 0) ? hi : f2bf(c - bf2f(hi));
            }
            Bs[row * LDSTR + 128 + sl] = v;
        }
        __syncthreads();

        int wm = (wv & 1) * 32;
        int wn = (wv >> 1) * 32;
        int fr = lane & 15;
        int kq = (lane >> 4) * 8;

        f32x4 zero = {0.0f, 0.0f, 0.0f, 0.0f};
        f32x4 acc00 = zero, acc01 = zero, acc10 = zero, acc11 = zero;
#pragma unroll
        for (int kc = 0; kc < KE; kc += 32) {
            int kk = kc + kq;
            bf16x8 a0 = *(const bf16x8*)&As[(wm + fr) * LDSTR + kk];
            bf16x8 a1 = *(const bf16x8*)&As[(wm + 16 + fr) * LDSTR + kk];
            bf16x8 b0 = *(const bf16x8*)&Bs[(wn + fr) * LDSTR + kk];
            bf16x8 b1 = *(const bf16x8*)&Bs[(wn + 16 + fr) * LDSTR + kk];
            acc00 = __builtin_amdgcn_mfma_f32_16x16x32_bf16(a0, b0, acc00, 0, 0, 0);
            acc01 = __builtin_amdgcn_mfma_f32_16x16x32_bf16(a0, b1, acc01, 0, 0, 0);
            acc10 = __builtin_amdgcn_mfma_f32_16x16x32_bf16(a1, b0, acc10, 0, 0, 0);
            acc11 = __builtin_amdgcn_mfma_f32_16x16x32_bf16(a1, b1, acc11, 0, 0, 0);
        }
        // every acc element is a finished sampled logit (const baked in via K-ext)
        float loss = 0.0f;
#pragma unroll
        for (int r = 0; r < 4; ++r) {
            float x;
            x = acc00[r]; loss += fmaxf(x, 0.0f) + log1pf(expf(-fabsf(x)));
            x = acc01[r]; loss += fmaxf(x, 0.0f) + log1pf(expf(-fabsf(x)));
            x = acc10[r]; loss += fmaxf(x, 0.0f) + log1pf(expf(-fabsf(x)));
            x = acc11[r]; loss += fmaxf(x, 0.0f) + log1pf(expf(-fabsf(x)));
        }
#pragma unroll
        for (int off = 32; off > 0; off >>= 1) loss += __shfl_xor(loss, off);
        if (lane == 0) red[wv] = loss;
        __syncthreads();
        if (tid == 0) partials[bid] = red[0] + red[1] + red[2] + red[3];
    } else {
        // ---- true-label path: wave-per-row, fp32 exact ----
        int b = (bid - NMAIN) * 4 + wv;
        int lbl = labels[b];
        float2 a = ((const float2*)pred)[(size_t)b * 64 + lane];
        float2 w = ((const float2*)weights)[(size_t)lbl * 64 + lane];
        float dot = a.x * w.x + a.y * w.y;
#pragma unroll
        for (int off = 32; off > 0; off >>= 1) dot += __shfl_xor(dot, off);
        if (lane == 0) {
            float x = dot + biases[lbl] + neg_log_expected(lbl);
            // sigmoid CE with z = 1/NTRUE = 1
            red[wv] = fmaxf(x, 0.0f) - x + log1pf(expf(-fabsf(x)));
        }
        __syncthreads();
        if (tid == 0) partials[bid] = red[0] + red[1] + red[2] + red[3];
    }
}

__global__ __launch_bounds__(256) void reduce_k(const float* __restrict__ partials,
                                                float* __restrict__ out) {
    int tid = threadIdx.x;
    float s = 0.0f;
    for (int i = tid; i < NBLK; i += 256) s += partials[i];
#pragma unroll
    for (int off = 32; off > 0; off >>= 1) s += __shfl_xor(s, off);
    __shared__ float r[4];
    if ((tid & 63) == 0) r[tid >> 6] = s;
    __syncthreads();
    if (tid == 0) out[0] = (r[0] + r[1] + r[2] + r[3]) * (1.0f / (float)BATCH);
}

extern "C" void kernel_launch(void* const* d_in, const int* in_sizes, int n_in,
                              void* d_out, int out_size, void* d_ws, size_t ws_size,
                              hipStream_t stream) {
    const float* pred    = (const float*)d_in[0];
    const float* weights = (const float*)d_in[1];
    const float* biases  = (const float*)d_in[2];
    const int*   labels  = (const int*)d_in[3];
    const int*   sampled = (const int*)d_in[4];

    float* partials = (float*)d_ws;   // 6144 floats = 24 KB (ws poison is unconditional; use is free)
    float* out = (float*)d_out;

    main_k<<<dim3(NBLK), dim3(256), 0, stream>>>(pred, weights, biases, labels, sampled, partials);
    reduce_k<<<dim3(1), dim3(256), 0, stream>>>(partials, out);
}

// Round 3
// 583.094 us; speedup vs baseline: 1.1427x; 1.0923x over previous
//
#include <hip/hip_runtime.h>
#include <hip/hip_bf16.h>

#define VOCAB 1000000
#define EMB 128
#define NEG 512
#define BATCH 16384

#define BM 64
#define BN 64
#define KE 160          // 128 real K + 32 ext slots (const folded into GEMM)
#define LDSTR 168       // LDS row stride in bf16 elems: 336B, 16B-aligned, 2-way-bank-free

#define NMAIN ((BATCH / BM) * (NEG / BN))   // 2048
#define TRUE_PER_BLK 16
#define NTRUE_BLK (BATCH / TRUE_PER_BLK)    // 1024 (16 rows/block, 4 per wave)
#define NPART (NMAIN + NTRUE_BLK)           // 3072

typedef __attribute__((ext_vector_type(8))) short bf16x8;
typedef __attribute__((ext_vector_type(4))) float f32x4;

static __device__ __forceinline__ unsigned short f2bf(float f) {
    union { __hip_bfloat16 b; unsigned short u; } cv;
    cv.b = __float2bfloat16(f);
    return cv.u;
}
static __device__ __forceinline__ float bf2f(unsigned short u) {
    union { unsigned short u; __hip_bfloat16 b; } cv;
    cv.u = u;
    return __bfloat162float(cv.b);
}

// -log(expected_count(c)) per TF LogUniformCandidateSampler.
// CRITICAL: p via log1p(1/(c+1)), NOT log(c+2)-log(c+1) — the latter
// cancels to 0 in fp32 for c ~ 1e6, giving E=0 -> -log(0)=inf -> NaN.
static __device__ __forceinline__ float neg_log_expected(int c) {
    float cf = (float)c;
    float p = log1pf(1.0f / (cf + 1.0f)) / logf((float)VOCAB + 1.0f);
    float E = -expm1f((float)NEG * log1pf(-p));
    return -logf(E);
}

// Fast sigmoid-CE softplus term: log(1+exp(-|x|)) via hardware exp/log.
// e in (0,1], 1+e in (1,2] — both intrinsics ~1 ulp there. Used only in
// the 8.4M-logit sampled epilogue (error averages out over the mean).
static __device__ __forceinline__ float softplus_negabs(float x) {
    return __logf(1.0f + __expf(-fabsf(x)));
}

// R0-proven prep: gather sampled weight rows -> bf16, append ext slots:
// slot128 = c_hi, slot129 = c_lo (2-way bf16 split of bias - log(E)), 130..159 = 0.
// Runs ONCE (512 blocks) — R2 showed fusing this into the 2048 GEMM blocks
// costs ~30us (per-block dependent gathers + transcendental chains).
__global__ __launch_bounds__(64) void prep_k(const float* __restrict__ weights,
                                             const float* __restrict__ biases,
                                             const int* __restrict__ sampled,
                                             unsigned short* __restrict__ swe) {
    int s = blockIdx.x;
    int t = threadIdx.x;
    int sid = sampled[s];
    unsigned short* row = swe + (size_t)s * KE;
    if (t < 32) {
        const float4* src = (const float4*)(weights + (size_t)sid * EMB);
        float4 v = src[t];
        uint2 p;
        p.x = (unsigned)f2bf(v.x) | ((unsigned)f2bf(v.y) << 16);
        p.y = (unsigned)f2bf(v.z) | ((unsigned)f2bf(v.w) << 16);
        *(uint2*)(row + t * 4) = p;
    } else {
        int slot = 128 + (t - 32);
        unsigned short v = 0;
        if (slot <= 129) {
            float c = biases[sid] + neg_log_expected(sid);
            unsigned short hi = f2bf(c);
            v = (slot == 128) ? hi : f2bf(c - bf2f(hi));
        }
        row[slot] = v;
    }
}

__global__ __launch_bounds__(256) void main_k(const float* __restrict__ pred,
                                              const float* __restrict__ weights,
                                              const float* __restrict__ biases,
                                              const int* __restrict__ labels,
                                              const unsigned short* __restrict__ swe,
                                              float* __restrict__ partials) {
    __shared__ unsigned short As[BM * LDSTR];
    __shared__ unsigned short Bs[BN * LDSTR];
    __shared__ float red[4];
    int bid = blockIdx.x;
    int tid = threadIdx.x;
    int lane = tid & 63;
    int wv = tid >> 6;

    if (bid < NMAIN) {
        // ---- sampled-logits GEMM tile: 64 rows x 64 samples ----
        // XCD-chunked swizzle (bijective, 2048 % 8 == 0): XCD (bid%8) gets a
        // contiguous run of 256 logical tiles -> each XCD's 1 MB pred chunk
        // is fetched from HBM once and reused 8x in its own L2 (pred is
        // HBM-cold every iteration: the 2 GB ws re-poison evicts L2/L3).
        int lg = ((bid & 7) << 8) | (bid >> 3);
        int m0 = (lg >> 3) * BM;
        int s0 = (lg & 7) * BN;

        // stage A (pred rows, fp32 -> bf16), k-contiguous
        const float4* pred4 = (const float4*)pred;
#pragma unroll
        for (int i = 0; i < 8; ++i) {
            int l = tid + i * 256;
            int row = l >> 5, k4 = l & 31;
            float4 v = pred4[(size_t)(m0 + row) * 32 + k4];
            uint2 p;
            p.x = (unsigned)f2bf(v.x) | ((unsigned)f2bf(v.y) << 16);
            p.y = (unsigned)f2bf(v.z) | ((unsigned)f2bf(v.w) << 16);
            *(uint2*)&As[row * LDSTR + k4 * 4] = p;
        }
        // stage A ext slots: [128]=[129]=1.0 (bf16 0x3F80), rest 0
#pragma unroll
        for (int i = 0; i < 8; ++i) {
            int l = tid + i * 256;
            int row = l >> 5, sl = l & 31;
            As[row * LDSTR + 128 + sl] = (sl < 2) ? (unsigned short)0x3F80 : (unsigned short)0;
        }
        // stage B (prepped bf16 rows incl. ext): 160 ushorts = 40 uint2 per row
#pragma unroll
        for (int i = 0; i < 10; ++i) {
            int l = tid + i * 256;
            int row = l / 40, j = l % 40;
            uint2 p = ((const uint2*)(swe + (size_t)(s0 + row) * KE))[j];
            *(uint2*)&Bs[row * LDSTR + j * 4] = p;
        }
        __syncthreads();

        int wm = (wv & 1) * 32;
        int wn = (wv >> 1) * 32;
        int fr = lane & 15;
        int kq = (lane >> 4) * 8;

        f32x4 zero = {0.0f, 0.0f, 0.0f, 0.0f};
        f32x4 acc00 = zero, acc01 = zero, acc10 = zero, acc11 = zero;
#pragma unroll
        for (int kc = 0; kc < KE; kc += 32) {
            int kk = kc + kq;
            bf16x8 a0 = *(const bf16x8*)&As[(wm + fr) * LDSTR + kk];
            bf16x8 a1 = *(const bf16x8*)&As[(wm + 16 + fr) * LDSTR + kk];
            bf16x8 b0 = *(const bf16x8*)&Bs[(wn + fr) * LDSTR + kk];
            bf16x8 b1 = *(const bf16x8*)&Bs[(wn + 16 + fr) * LDSTR + kk];
            acc00 = __builtin_amdgcn_mfma_f32_16x16x32_bf16(a0, b0, acc00, 0, 0, 0);
            acc01 = __builtin_amdgcn_mfma_f32_16x16x32_bf16(a0, b1, acc01, 0, 0, 0);
            acc10 = __builtin_amdgcn_mfma_f32_16x16x32_bf16(a1, b0, acc10, 0, 0, 0);
            acc11 = __builtin_amdgcn_mfma_f32_16x16x32_bf16(a1, b1, acc11, 0, 0, 0);
        }
        // every acc element is a finished sampled logit (const baked in via K-ext)
        float loss = 0.0f;
#pragma unroll
        for (int r = 0; r < 4; ++r) {
            float x;
            x = acc00[r]; loss += fmaxf(x, 0.0f) + softplus_negabs(x);
            x = acc01[r]; loss += fmaxf(x, 0.0f) + softplus_negabs(x);
            x = acc10[r]; loss += fmaxf(x, 0.0f) + softplus_negabs(x);
            x = acc11[r]; loss += fmaxf(x, 0.0f) + softplus_negabs(x);
        }
#pragma unroll
        for (int off = 32; off > 0; off >>= 1) loss += __shfl_xor(loss, off);
        if (lane == 0) red[wv] = loss;
        __syncthreads();
        if (tid == 0) partials[bid] = red[0] + red[1] + red[2] + red[3];
    } else {
        // ---- true-label path: 16 rows/block, 4 per wave, fp32 exact ----
        int b0 = (bid - NMAIN) * TRUE_PER_BLK + wv * 4;
        float lsum = 0.0f;
#pragma unroll
        for (int j = 0; j < 4; ++j) {
            int b = b0 + j;
            int lbl = labels[b];
            float2 a = ((const float2*)pred)[(size_t)b * 64 + lane];
            float2 w = ((const float2*)weights)[(size_t)lbl * 64 + lane];
            float dot = a.x * w.x + a.y * w.y;
#pragma unroll
            for (int off = 32; off > 0; off >>= 1) dot += __shfl_xor(dot, off);
            if (lane == 0) {
                float x = dot + biases[lbl] + neg_log_expected(lbl);
                // sigmoid CE with z = 1/NTRUE = 1 (exact path: only 16384 terms)
                lsum += fmaxf(x, 0.0f) - x + log1pf(expf(-fabsf(x)));
            }
        }
        if (lane == 0) red[wv] = lsum;
        __syncthreads();
        if (tid == 0) partials[bid] = red[0] + red[1] + red[2] + red[3];
    }
}

__global__ __launch_bounds__(256) void reduce_k(const float* __restrict__ partials,
                                                float* __restrict__ out) {
    int tid = threadIdx.x;
    float s = 0.0f;
    for (int i = tid; i < NPART; i += 256) s += partials[i];
#pragma unroll
    for (int off = 32; off > 0; off >>= 1) s += __shfl_xor(s, off);
    __shared__ float r[4];
    if ((tid & 63) == 0) r[tid >> 6] = s;
    __syncthreads();
    if (tid == 0) out[0] = (r[0] + r[1] + r[2] + r[3]) * (1.0f / (float)BATCH);
}

extern "C" void kernel_launch(void* const* d_in, const int* in_sizes, int n_in,
                              void* d_out, int out_size, void* d_ws, size_t ws_size,
                              hipStream_t stream) {
    const float* pred    = (const float*)d_in[0];
    const float* weights = (const float*)d_in[1];
    const float* biases  = (const float*)d_in[2];
    const int*   labels  = (const int*)d_in[3];
    const int*   sampled = (const int*)d_in[4];

    unsigned short* swe = (unsigned short*)d_ws;
    float* partials = (float*)((char*)d_ws + (size_t)NEG * KE * sizeof(unsigned short));
    float* out = (float*)d_out;

    prep_k<<<dim3(NEG), dim3(64), 0, stream>>>(weights, biases, sampled, swe);
    main_k<<<dim3(NPART), dim3(256), 0, stream>>>(pred, weights, biases, labels, swe, partials);
    reduce_k<<<dim3(1), dim3(256), 0, stream>>>(partials, out);
}